// Round 1
// baseline (420.225 us; speedup 1.0000x reference)
//
#include <hip/hip_runtime.h>
#include <hip/hip_bf16.h>
#include <math.h>

// Problem constants (S=1024, B=2 -> T=2048)
#define T_  2048
#define H_  1024
#define F_  4096
#define E_  4
#define EF_ (E_*F_)

typedef __attribute__((ext_vector_type(8))) short short8;   // 8 bf16 = 4 VGPRs
typedef __attribute__((ext_vector_type(4))) float f32x4;    // MFMA 16x16 accumulator

#define BM 128
#define BN 128
#define BK 64

__device__ __forceinline__ void async_copy16(const void* g, void* l) {
    // global -> LDS direct DMA, 16B/lane; LDS dest is wave-uniform base + lane*16
    __builtin_amdgcn_global_load_lds(
        (const __attribute__((address_space(1))) void*)g,
        (__attribute__((address_space(3))) void*)l, 16, 0, 0);
}

__global__ __launch_bounds__(256)
void convert_x_kernel(const float* __restrict__ x, __hip_bfloat16* __restrict__ xb) {
    int i = blockIdx.x * 256 + threadIdx.x;   // grid sized exactly T_*H_/256
    xb[i] = __float2bfloat16(x[i]);
}

// w1 [E][H][F] fp32  ->  w1t [E][F][H] bf16   (B^T layout for GEMM1: rows=F(N), cols=H(K))
__global__ __launch_bounds__(256)
void trans_w1_kernel(const float* __restrict__ w1, __hip_bfloat16* __restrict__ w1t) {
    __shared__ float tile[32][33];
    const int e = blockIdx.z;
    const int f0 = blockIdx.x * 32, h0 = blockIdx.y * 32;
    const float* src = w1 + (size_t)e * H_ * F_;
    __hip_bfloat16* dst = w1t + (size_t)e * F_ * H_;
    const int tx = threadIdx.x, ty = threadIdx.y;
#pragma unroll
    for (int i = 0; i < 32; i += 8)
        tile[ty + i][tx] = src[(size_t)(h0 + ty + i) * F_ + f0 + tx];
    __syncthreads();
#pragma unroll
    for (int i = 0; i < 32; i += 8)
        dst[(size_t)(f0 + ty + i) * H_ + h0 + tx] = __float2bfloat16(tile[tx][ty + i]);
}

// w2 [E][F][H] fp32  ->  w2t [H][E*F] bf16    (B^T layout for GEMM2: rows=H(N), cols=E*F(K))
__global__ __launch_bounds__(256)
void trans_w2_kernel(const float* __restrict__ w2, __hip_bfloat16* __restrict__ w2t) {
    __shared__ float tile[32][33];
    const int e = blockIdx.z;
    const int h0 = blockIdx.x * 32, f0 = blockIdx.y * 32;
    const float* src = w2 + (size_t)e * F_ * H_;
    const int tx = threadIdx.x, ty = threadIdx.y;
#pragma unroll
    for (int i = 0; i < 32; i += 8)
        tile[ty + i][tx] = src[(size_t)(f0 + ty + i) * H_ + h0 + tx];
    __syncthreads();
#pragma unroll
    for (int i = 0; i < 32; i += 8)
        w2t[(size_t)(h0 + ty + i) * EF_ + (size_t)e * F_ + f0 + tx] =
            __float2bfloat16(tile[tx][ty + i]);
}

// GEMM1: A''[t][e*F+f] = bf16( p[t,e] * gelu( (X @ W1_e)[t,f] ) )
// A = Xb [T][H] bf16 row-major, Bt = w1t[e] [F][H] bf16 (B^T)
__global__ __launch_bounds__(256)
void gemm1_kernel(const __hip_bfloat16* __restrict__ Xb,
                  const __hip_bfloat16* __restrict__ W1t,
                  const float* __restrict__ probs,
                  __hip_bfloat16* __restrict__ Aout) {
    const int e  = blockIdx.z;
    const int n0 = blockIdx.x * BN;   // over F
    const int m0 = blockIdx.y * BM;   // over T
    const __hip_bfloat16* Bt = W1t + (size_t)e * F_ * H_;
    __shared__ __align__(16) __hip_bfloat16 As[BM * BK];  // [m][k]
    __shared__ __align__(16) __hip_bfloat16 Bs[BN * BK];  // [n][k]
    const int tid = threadIdx.x, lane = tid & 63, wave = tid >> 6;
    const int wm = (wave >> 1) * 64, wn = (wave & 1) * 64;
    const int lr = lane >> 3;          // 0..7 (tile row within 8-row stripe)
    const int lc = (lane & 7) * 8;     // 0..56 (k offset, 8 bf16 = 16B)

    f32x4 acc[4][4];
#pragma unroll
    for (int mi = 0; mi < 4; mi++)
#pragma unroll
        for (int ni = 0; ni < 4; ni++) acc[mi][ni] = (f32x4){0.f, 0.f, 0.f, 0.f};

    for (int k0 = 0; k0 < H_; k0 += BK) {
#pragma unroll
        for (int j = 0; j < 4; j++) {
            const int i = wave * 4 + j;
            const int r = i * 8 + lr;
            async_copy16(Xb + (size_t)(m0 + r) * H_ + (k0 + lc), (char*)As + i * 1024);
            async_copy16(Bt + (size_t)(n0 + r) * H_ + (k0 + lc), (char*)Bs + i * 1024);
        }
        __syncthreads();
#pragma unroll
        for (int kt = 0; kt < BK / 32; kt++) {
            const int ko = kt * 32 + (lane >> 4) * 8;
            const int mr = lane & 15;
            short8 aF[4], bF[4];
#pragma unroll
            for (int mi = 0; mi < 4; mi++)
                aF[mi] = *(const short8*)&As[(wm + mi * 16 + mr) * BK + ko];
#pragma unroll
            for (int ni = 0; ni < 4; ni++)
                bF[ni] = *(const short8*)&Bs[(wn + ni * 16 + mr) * BK + ko];
#pragma unroll
            for (int mi = 0; mi < 4; mi++)
#pragma unroll
                for (int ni = 0; ni < 4; ni++)
                    acc[mi][ni] = __builtin_amdgcn_mfma_f32_16x16x32_bf16(
                        aF[mi], bF[ni], acc[mi][ni], 0, 0, 0);
        }
        __syncthreads();
    }
    // C/D layout (measured m89/m91): col = lane&15, row = (lane>>4)*4 + reg
    const int rq = (lane >> 4) * 4, cq = lane & 15;
#pragma unroll
    for (int mi = 0; mi < 4; mi++) {
#pragma unroll
        for (int reg = 0; reg < 4; reg++) {
            const int row = m0 + wm + mi * 16 + rq + reg;
            const float pv = probs[(size_t)row * E_ + e];
#pragma unroll
            for (int ni = 0; ni < 4; ni++) {
                const int col = n0 + wn + ni * 16 + cq;
                const float v = acc[mi][ni][reg];
                const float g = 0.5f * v * (1.0f + erff(v * 0.70710678118654752f)); // exact gelu
                Aout[(size_t)row * EF_ + (size_t)e * F_ + col] = __float2bfloat16(g * pv);
            }
        }
    }
}

// GEMM2 (split-K by expert slice z): out[t][h] += (A'' @ W2'')[t][h] over k in [z*F,(z+1)*F)
// out pre-initialized with residual.
__global__ __launch_bounds__(256)
void gemm2_kernel(const __hip_bfloat16* __restrict__ Ain,   // [T][EF]
                  const __hip_bfloat16* __restrict__ W2t,   // [H][EF]
                  float* __restrict__ out) {                // [T][H]
    const int z  = blockIdx.z;
    const int n0 = blockIdx.x * BN;   // over H
    const int m0 = blockIdx.y * BM;   // over T
    const int kbase = z * F_;
    __shared__ __align__(16) __hip_bfloat16 As[BM * BK];
    __shared__ __align__(16) __hip_bfloat16 Bs[BN * BK];
    const int tid = threadIdx.x, lane = tid & 63, wave = tid >> 6;
    const int wm = (wave >> 1) * 64, wn = (wave & 1) * 64;
    const int lr = lane >> 3;
    const int lc = (lane & 7) * 8;

    f32x4 acc[4][4];
#pragma unroll
    for (int mi = 0; mi < 4; mi++)
#pragma unroll
        for (int ni = 0; ni < 4; ni++) acc[mi][ni] = (f32x4){0.f, 0.f, 0.f, 0.f};

    for (int k0 = kbase; k0 < kbase + F_; k0 += BK) {
#pragma unroll
        for (int j = 0; j < 4; j++) {
            const int i = wave * 4 + j;
            const int r = i * 8 + lr;
            async_copy16(Ain + (size_t)(m0 + r) * EF_ + (k0 + lc), (char*)As + i * 1024);
            async_copy16(W2t + (size_t)(n0 + r) * EF_ + (k0 + lc), (char*)Bs + i * 1024);
        }
        __syncthreads();
#pragma unroll
        for (int kt = 0; kt < BK / 32; kt++) {
            const int ko = kt * 32 + (lane >> 4) * 8;
            const int mr = lane & 15;
            short8 aF[4], bF[4];
#pragma unroll
            for (int mi = 0; mi < 4; mi++)
                aF[mi] = *(const short8*)&As[(wm + mi * 16 + mr) * BK + ko];
#pragma unroll
            for (int ni = 0; ni < 4; ni++)
                bF[ni] = *(const short8*)&Bs[(wn + ni * 16 + mr) * BK + ko];
#pragma unroll
            for (int mi = 0; mi < 4; mi++)
#pragma unroll
                for (int ni = 0; ni < 4; ni++)
                    acc[mi][ni] = __builtin_amdgcn_mfma_f32_16x16x32_bf16(
                        aF[mi], bF[ni], acc[mi][ni], 0, 0, 0);
        }
        __syncthreads();
    }
    const int rq = (lane >> 4) * 4, cq = lane & 15;
#pragma unroll
    for (int mi = 0; mi < 4; mi++)
#pragma unroll
        for (int ni = 0; ni < 4; ni++)
#pragma unroll
            for (int reg = 0; reg < 4; reg++) {
                const int row = m0 + wm + mi * 16 + rq + reg;
                const int col = n0 + wn + ni * 16 + cq;
                atomicAdd(&out[(size_t)row * H_ + col], acc[mi][ni][reg]);
            }
}

extern "C" void kernel_launch(void* const* d_in, const int* in_sizes, int n_in,
                              void* d_out, int out_size, void* d_ws, size_t ws_size,
                              hipStream_t stream) {
    const float* x     = (const float*)d_in[0];  // hidden_states [S,B,H] = [T,H]
    const float* res   = (const float*)d_in[1];  // mlp_residual  [T,H]
    const float* probs = (const float*)d_in[2];  // [T,E] (already zero off-route)
    // d_in[3] = routing_map: redundant (probs already masked) — unused
    const float* w1    = (const float*)d_in[4];  // [E,H,F]
    const float* w2    = (const float*)d_in[5];  // [E,F,H]
    float* out = (float*)d_out;

    char* ws = (char*)d_ws;
    __hip_bfloat16* Xb   = (__hip_bfloat16*)(ws);                              //  4 MB
    __hip_bfloat16* W1t  = (__hip_bfloat16*)(ws + (4u << 20));                 // 32 MB
    __hip_bfloat16* W2t  = (__hip_bfloat16*)(ws + (4u << 20) + (32u << 20));   // 32 MB
    __hip_bfloat16* Aout = (__hip_bfloat16*)(ws + (4u << 20) + (64u << 20));   // 64 MB

    // out = residual (then GEMM2 accumulates into it)
    hipMemcpyAsync(out, res, (size_t)T_ * H_ * sizeof(float),
                   hipMemcpyDeviceToDevice, stream);

    convert_x_kernel<<<dim3(T_ * H_ / 256), dim3(256), 0, stream>>>(x, Xb);
    trans_w1_kernel<<<dim3(F_ / 32, H_ / 32, E_), dim3(32, 8), 0, stream>>>(w1, W1t);
    trans_w2_kernel<<<dim3(H_ / 32, F_ / 32, E_), dim3(32, 8), 0, stream>>>(w2, W2t);
    gemm1_kernel<<<dim3(F_ / BN, T_ / BM, E_), dim3(256), 0, stream>>>(Xb, W1t, probs, Aout);
    gemm2_kernel<<<dim3(H_ / BN, T_ / BM, E_), dim3(256), 0, stream>>>(Aout, W2t, out);
}

// Round 2
// 399.321 us; speedup vs baseline: 1.0523x; 1.0523x over previous
//
#include <hip/hip_runtime.h>
#include <hip/hip_bf16.h>
#include <math.h>

// Problem constants (S=1024, B=2 -> T=2048)
#define T_  2048
#define H_  1024
#define F_  4096
#define E_  4
#define EF_ (E_*F_)

typedef __attribute__((ext_vector_type(8))) short short8;   // 8 bf16 = 4 VGPRs
typedef __attribute__((ext_vector_type(4))) float f32x4;    // MFMA 16x16 accumulator

#define BM 128
#define BN 128
#define BK 64

__device__ __forceinline__ void async_copy16(const void* g, void* l) {
    // global -> LDS direct DMA, 16B/lane; LDS dest is wave-uniform base + lane*16
    __builtin_amdgcn_global_load_lds(
        (const __attribute__((address_space(1))) void*)g,
        (__attribute__((address_space(3))) void*)l, 16, 0, 0);
}

__global__ __launch_bounds__(256)
void convert_x_kernel(const float* __restrict__ x, __hip_bfloat16* __restrict__ xb) {
    int i = blockIdx.x * 256 + threadIdx.x;   // grid sized exactly T_*H_/256
    xb[i] = __float2bfloat16(x[i]);
}

// w1 [E][H][F] fp32  ->  w1t [E][F][H] bf16   (B^T layout for GEMM1: rows=F(N), cols=H(K))
__global__ __launch_bounds__(256)
void trans_w1_kernel(const float* __restrict__ w1, __hip_bfloat16* __restrict__ w1t) {
    __shared__ float tile[32][33];
    const int e = blockIdx.z;
    const int f0 = blockIdx.x * 32, h0 = blockIdx.y * 32;
    const float* src = w1 + (size_t)e * H_ * F_;
    __hip_bfloat16* dst = w1t + (size_t)e * F_ * H_;
    const int tx = threadIdx.x, ty = threadIdx.y;
#pragma unroll
    for (int i = 0; i < 32; i += 8)
        tile[ty + i][tx] = src[(size_t)(h0 + ty + i) * F_ + f0 + tx];
    __syncthreads();
#pragma unroll
    for (int i = 0; i < 32; i += 8)
        dst[(size_t)(f0 + ty + i) * H_ + h0 + tx] = __float2bfloat16(tile[tx][ty + i]);
}

// w2 [E][F][H] fp32  ->  w2t [H][E*F] bf16    (B^T layout for GEMM2: rows=H(N), cols=E*F(K))
__global__ __launch_bounds__(256)
void trans_w2_kernel(const float* __restrict__ w2, __hip_bfloat16* __restrict__ w2t) {
    __shared__ float tile[32][33];
    const int e = blockIdx.z;
    const int h0 = blockIdx.x * 32, f0 = blockIdx.y * 32;
    const float* src = w2 + (size_t)e * F_ * H_;
    const int tx = threadIdx.x, ty = threadIdx.y;
#pragma unroll
    for (int i = 0; i < 32; i += 8)
        tile[ty + i][tx] = src[(size_t)(f0 + ty + i) * H_ + h0 + tx];
    __syncthreads();
#pragma unroll
    for (int i = 0; i < 32; i += 8)
        w2t[(size_t)(h0 + ty + i) * EF_ + (size_t)e * F_ + f0 + tx] =
            __float2bfloat16(tile[tx][ty + i]);
}

// LDS layout: row r (128 B = 8 chunks of 16 B), chunk c stored at position c ^ (r&7).
// Staging achieves this by fetching global chunk (lane&7)^(lane>>3) per lane (the LDS
// side of global_load_lds is fixed at base+lane*16); readers XOR the chunk index.
// Result: 16 rows x same-k fragment reads spread over 8 chunk columns -> 2 lanes/bank
// (free, m136) instead of 16-way conflict.

// GEMM1: A''[t][e*F+f] = bf16( p[t,e] * gelu( (X @ W1_e)[t,f] ) )
__global__ __launch_bounds__(256)
void gemm1_kernel(const __hip_bfloat16* __restrict__ Xb,
                  const __hip_bfloat16* __restrict__ W1t,
                  const float* __restrict__ probs,
                  __hip_bfloat16* __restrict__ Aout) {
    const int e  = blockIdx.z;
    const int n0 = blockIdx.x * BN;   // over F
    const int m0 = blockIdx.y * BM;   // over T
    const __hip_bfloat16* Bt = W1t + (size_t)e * F_ * H_;
    __shared__ __align__(16) __hip_bfloat16 As[BM * BK];  // [m][k], k-chunks swizzled
    __shared__ __align__(16) __hip_bfloat16 Bs[BN * BK];  // [n][k], k-chunks swizzled
    const int tid = threadIdx.x, lane = tid & 63, wave = tid >> 6;
    const int wm = (wave >> 1) * 64, wn = (wave & 1) * 64;
    const int lr  = lane >> 3;                    // row within 8-row stripe
    const int lcg = ((lane & 7) ^ lr) * 8;        // swizzled global k-offset (elements)

    f32x4 acc[4][4];
#pragma unroll
    for (int mi = 0; mi < 4; mi++)
#pragma unroll
        for (int ni = 0; ni < 4; ni++) acc[mi][ni] = (f32x4){0.f, 0.f, 0.f, 0.f};

    for (int k0 = 0; k0 < H_; k0 += BK) {
#pragma unroll
        for (int j = 0; j < 4; j++) {
            const int i = wave * 4 + j;
            const int r = i * 8 + lr;
            async_copy16(Xb + (size_t)(m0 + r) * H_ + (k0 + lcg), (char*)As + i * 1024);
            async_copy16(Bt + (size_t)(n0 + r) * H_ + (k0 + lcg), (char*)Bs + i * 1024);
        }
        __syncthreads();
#pragma unroll
        for (int kt = 0; kt < BK / 32; kt++) {
            const int kq = kt * 4 + (lane >> 4);  // 16B-chunk index within row, 0..7
            const int mr = lane & 15;
            const int sw = mr & 7;                // row&7 (wm, mi*16 are mult of 16)
            short8 aF[4], bF[4];
#pragma unroll
            for (int mi = 0; mi < 4; mi++)
                aF[mi] = *(const short8*)&As[(wm + mi * 16 + mr) * BK + ((kq ^ sw) << 3)];
#pragma unroll
            for (int ni = 0; ni < 4; ni++)
                bF[ni] = *(const short8*)&Bs[(wn + ni * 16 + mr) * BK + ((kq ^ sw) << 3)];
#pragma unroll
            for (int mi = 0; mi < 4; mi++)
#pragma unroll
                for (int ni = 0; ni < 4; ni++)
                    acc[mi][ni] = __builtin_amdgcn_mfma_f32_16x16x32_bf16(
                        aF[mi], bF[ni], acc[mi][ni], 0, 0, 0);
        }
        __syncthreads();
    }
    // C/D layout (measured m89/m91): col = lane&15, row = (lane>>4)*4 + reg
    const int rq = (lane >> 4) * 4, cq = lane & 15;
#pragma unroll
    for (int mi = 0; mi < 4; mi++) {
#pragma unroll
        for (int reg = 0; reg < 4; reg++) {
            const int row = m0 + wm + mi * 16 + rq + reg;
            const float pv = probs[(size_t)row * E_ + e];
#pragma unroll
            for (int ni = 0; ni < 4; ni++) {
                const int col = n0 + wn + ni * 16 + cq;
                const float v = acc[mi][ni][reg];
                const float g = 0.5f * v * (1.0f + erff(v * 0.70710678118654752f)); // exact gelu
                Aout[(size_t)row * EF_ + (size_t)e * F_ + col] = __float2bfloat16(g * pv);
            }
        }
    }
}

// GEMM2 (split-K by expert slice z): out[t][h] += (A'' @ W2'')[t][h] over k in [z*F,(z+1)*F)
// out pre-initialized with residual.
__global__ __launch_bounds__(256)
void gemm2_kernel(const __hip_bfloat16* __restrict__ Ain,   // [T][EF]
                  const __hip_bfloat16* __restrict__ W2t,   // [H][EF]
                  float* __restrict__ out) {                // [T][H]
    const int z  = blockIdx.z;
    const int n0 = blockIdx.x * BN;   // over H
    const int m0 = blockIdx.y * BM;   // over T
    const int kbase = z * F_;
    __shared__ __align__(16) __hip_bfloat16 As[BM * BK];
    __shared__ __align__(16) __hip_bfloat16 Bs[BN * BK];
    const int tid = threadIdx.x, lane = tid & 63, wave = tid >> 6;
    const int wm = (wave >> 1) * 64, wn = (wave & 1) * 64;
    const int lr  = lane >> 3;
    const int lcg = ((lane & 7) ^ lr) * 8;        // swizzled global k-offset

    f32x4 acc[4][4];
#pragma unroll
    for (int mi = 0; mi < 4; mi++)
#pragma unroll
        for (int ni = 0; ni < 4; ni++) acc[mi][ni] = (f32x4){0.f, 0.f, 0.f, 0.f};

    for (int k0 = kbase; k0 < kbase + F_; k0 += BK) {
#pragma unroll
        for (int j = 0; j < 4; j++) {
            const int i = wave * 4 + j;
            const int r = i * 8 + lr;
            async_copy16(Ain + (size_t)(m0 + r) * EF_ + (k0 + lcg), (char*)As + i * 1024);
            async_copy16(W2t + (size_t)(n0 + r) * EF_ + (k0 + lcg), (char*)Bs + i * 1024);
        }
        __syncthreads();
#pragma unroll
        for (int kt = 0; kt < BK / 32; kt++) {
            const int kq = kt * 4 + (lane >> 4);
            const int mr = lane & 15;
            const int sw = mr & 7;
            short8 aF[4], bF[4];
#pragma unroll
            for (int mi = 0; mi < 4; mi++)
                aF[mi] = *(const short8*)&As[(wm + mi * 16 + mr) * BK + ((kq ^ sw) << 3)];
#pragma unroll
            for (int ni = 0; ni < 4; ni++)
                bF[ni] = *(const short8*)&Bs[(wn + ni * 16 + mr) * BK + ((kq ^ sw) << 3)];
#pragma unroll
            for (int mi = 0; mi < 4; mi++)
#pragma unroll
                for (int ni = 0; ni < 4; ni++)
                    acc[mi][ni] = __builtin_amdgcn_mfma_f32_16x16x32_bf16(
                        aF[mi], bF[ni], acc[mi][ni], 0, 0, 0);
        }
        __syncthreads();
    }
    const int rq = (lane >> 4) * 4, cq = lane & 15;
#pragma unroll
    for (int mi = 0; mi < 4; mi++)
#pragma unroll
        for (int ni = 0; ni < 4; ni++)
#pragma unroll
            for (int reg = 0; reg < 4; reg++) {
                const int row = m0 + wm + mi * 16 + rq + reg;
                const int col = n0 + wn + ni * 16 + cq;
                atomicAdd(&out[(size_t)row * H_ + col], acc[mi][ni][reg]);
            }
}

extern "C" void kernel_launch(void* const* d_in, const int* in_sizes, int n_in,
                              void* d_out, int out_size, void* d_ws, size_t ws_size,
                              hipStream_t stream) {
    const float* x     = (const float*)d_in[0];  // hidden_states [S,B,H] = [T,H]
    const float* res   = (const float*)d_in[1];  // mlp_residual  [T,H]
    const float* probs = (const float*)d_in[2];  // [T,E] (already zero off-route)
    // d_in[3] = routing_map: redundant (probs already masked) — unused
    const float* w1    = (const float*)d_in[4];  // [E,H,F]
    const float* w2    = (const float*)d_in[5];  // [E,F,H]
    float* out = (float*)d_out;

    char* ws = (char*)d_ws;
    __hip_bfloat16* Xb   = (__hip_bfloat16*)(ws);                              //  4 MB
    __hip_bfloat16* W1t  = (__hip_bfloat16*)(ws + (4u << 20));                 // 32 MB
    __hip_bfloat16* W2t  = (__hip_bfloat16*)(ws + (4u << 20) + (32u << 20));   // 32 MB
    __hip_bfloat16* Aout = (__hip_bfloat16*)(ws + (4u << 20) + (64u << 20));   // 64 MB

    // out = residual (then GEMM2 accumulates into it)
    hipMemcpyAsync(out, res, (size_t)T_ * H_ * sizeof(float),
                   hipMemcpyDeviceToDevice, stream);

    convert_x_kernel<<<dim3(T_ * H_ / 256), dim3(256), 0, stream>>>(x, Xb);
    trans_w1_kernel<<<dim3(F_ / 32, H_ / 32, E_), dim3(32, 8), 0, stream>>>(w1, W1t);
    trans_w2_kernel<<<dim3(H_ / 32, F_ / 32, E_), dim3(32, 8), 0, stream>>>(w2, W2t);
    gemm1_kernel<<<dim3(F_ / BN, T_ / BM, E_), dim3(256), 0, stream>>>(Xb, W1t, probs, Aout);
    gemm2_kernel<<<dim3(H_ / BN, T_ / BM, E_), dim3(256), 0, stream>>>(Aout, W2t, out);
}

// Round 4
// 339.316 us; speedup vs baseline: 1.2384x; 1.1768x over previous
//
#include <hip/hip_runtime.h>
#include <hip/hip_bf16.h>
#include <math.h>

// Problem constants (S=1024, B=2 -> T=2048)
#define T_  2048
#define H_  1024
#define F_  4096
#define E_  4
#define EF_ (E_*F_)
#define ROWCAP 4608   // sum_e ceil(cnt_e/128)*128 <= 4096 + 4*127 = 4604

typedef __attribute__((ext_vector_type(8))) short short8;   // 8 bf16 = 4 VGPRs
typedef __attribute__((ext_vector_type(4))) float f32x4;    // MFMA 16x16 accumulator

#define BM 128
#define BN 128
#define BK 64

__device__ __forceinline__ void async_copy16(const void* g, void* l) {
    __builtin_amdgcn_global_load_lds(
        (const __attribute__((address_space(1))) void*)g,
        (__attribute__((address_space(3))) void*)l, 16, 0, 0);
}

__device__ __forceinline__ float bf2f(unsigned short u) {
    return __uint_as_float(((unsigned)u) << 16);
}

__global__ __launch_bounds__(256)
void convert_x_kernel(const float* __restrict__ x, __hip_bfloat16* __restrict__ xb) {
    int i = blockIdx.x * 256 + threadIdx.x;
    xb[i] = __float2bfloat16(x[i]);
}

// w1 [E][H][F] fp32 -> w1t [E][F][H] bf16 (B^T for GEMM1)
__global__ __launch_bounds__(256)
void trans_w1_kernel(const float* __restrict__ w1, __hip_bfloat16* __restrict__ w1t) {
    __shared__ float tile[32][33];
    const int e = blockIdx.z;
    const int f0 = blockIdx.x * 32, h0 = blockIdx.y * 32;
    const float* src = w1 + (size_t)e * H_ * F_;
    __hip_bfloat16* dst = w1t + (size_t)e * F_ * H_;
    const int tx = threadIdx.x, ty = threadIdx.y;
#pragma unroll
    for (int i = 0; i < 32; i += 8)
        tile[ty + i][tx] = src[(size_t)(h0 + ty + i) * F_ + f0 + tx];
    __syncthreads();
#pragma unroll
    for (int i = 0; i < 32; i += 8)
        dst[(size_t)(f0 + ty + i) * H_ + h0 + tx] = __float2bfloat16(tile[tx][ty + i]);
}

// w2 [E][F][H] fp32 -> w2t [H][E*F] bf16 (B^T for GEMM2)
__global__ __launch_bounds__(256)
void trans_w2_kernel(const float* __restrict__ w2, __hip_bfloat16* __restrict__ w2t) {
    __shared__ float tile[32][33];
    const int e = blockIdx.z;
    const int h0 = blockIdx.x * 32, f0 = blockIdx.y * 32;
    const float* src = w2 + (size_t)e * F_ * H_;
    const int tx = threadIdx.x, ty = threadIdx.y;
#pragma unroll
    for (int i = 0; i < 32; i += 8)
        tile[ty + i][tx] = src[(size_t)(f0 + ty + i) * H_ + h0 + tx];
    __syncthreads();
#pragma unroll
    for (int i = 0; i < 32; i += 8)
        w2t[(size_t)(h0 + ty + i) * EF_ + (size_t)e * F_ + f0 + tx] =
            __float2bfloat16(tile[tx][ty + i]);
}

// Routing: probs>0 iff routed (probs is masked-renormalized softmax; exactly TOPK=2/token).
__global__ __launch_bounds__(256)
void build_lists_kernel(const float* __restrict__ probs, int* __restrict__ cnt,
                        int* __restrict__ list, int* __restrict__ slot) {
    int t = blockIdx.x * 256 + threadIdx.x;
#pragma unroll
    for (int e = 0; e < E_; e++) {
        if (probs[t * E_ + e] > 0.0f) {
            int pos = atomicAdd(&cnt[e], 1);
            list[e * T_ + pos] = t;
            slot[t * E_ + e] = pos;
        }
    }
}

__global__ void prefix_kernel(const int* __restrict__ cnt, int* __restrict__ off) {
    if (threadIdx.x == 0) {
        int acc = 0;
#pragma unroll
        for (int e = 0; e < E_; e++) { off[e] = acc; acc += (cnt[e] + 127) & ~127; }
        off[E_] = acc;
    }
}

// LDS swizzle (kept from R2): row r chunk c stored at c ^ (r&7); staging fetches the
// permuted global chunk per lane; readers XOR. Conflict-free (verified: 2.5e7 -> 0).

// GEMM1 (gathered): Ag[off[e]+i][f] = bf16( p * gelu( (X[list[e][i]] @ W1_e)[f] ) )
__global__ __launch_bounds__(256)
void gemm1_kernel(const __hip_bfloat16* __restrict__ Xb,
                  const __hip_bfloat16* __restrict__ W1t,
                  const float* __restrict__ probs,
                  const int* __restrict__ cnt, const int* __restrict__ off,
                  const int* __restrict__ list,
                  __hip_bfloat16* __restrict__ Ag) {
    const int e  = blockIdx.z;
    const int ce = cnt[e];
    const int m0 = blockIdx.y * BM;
    if (m0 >= ce) return;
    const int n0 = blockIdx.x * BN;   // over F
    const __hip_bfloat16* Bt = W1t + (size_t)e * F_ * H_;
    __shared__ __align__(16) __hip_bfloat16 As[BM * BK];
    __shared__ __align__(16) __hip_bfloat16 Bs[BN * BK];
    const int tid = threadIdx.x, lane = tid & 63, wave = tid >> 6;
    const int wm = (wave >> 1) * 64, wn = (wave & 1) * 64;
    const int lr  = lane >> 3;
    const int lcg = ((lane & 7) ^ lr) * 8;

    int tokA[4];
#pragma unroll
    for (int j = 0; j < 4; j++) {
        int idx = m0 + (wave * 4 + j) * 8 + lr;
        if (idx >= ce) idx = ce - 1;          // clamp: dup row, store discarded below
        tokA[j] = list[e * T_ + idx];
    }

    f32x4 acc[4][4];
#pragma unroll
    for (int mi = 0; mi < 4; mi++)
#pragma unroll
        for (int ni = 0; ni < 4; ni++) acc[mi][ni] = (f32x4){0.f, 0.f, 0.f, 0.f};

    for (int k0 = 0; k0 < H_; k0 += BK) {
#pragma unroll
        for (int j = 0; j < 4; j++) {
            const int i = wave * 4 + j;
            const int r = i * 8 + lr;
            async_copy16(Xb + (size_t)tokA[j] * H_ + (k0 + lcg), (char*)As + i * 1024);
            async_copy16(Bt + (size_t)(n0 + r) * H_ + (k0 + lcg), (char*)Bs + i * 1024);
        }
        __syncthreads();
#pragma unroll
        for (int kt = 0; kt < BK / 32; kt++) {
            const int kq = kt * 4 + (lane >> 4);
            const int mr = lane & 15;
            const int sw = mr & 7;
            short8 aF[4], bF[4];
#pragma unroll
            for (int mi = 0; mi < 4; mi++)
                aF[mi] = *(const short8*)&As[(wm + mi * 16 + mr) * BK + ((kq ^ sw) << 3)];
#pragma unroll
            for (int ni = 0; ni < 4; ni++)
                bF[ni] = *(const short8*)&Bs[(wn + ni * 16 + mr) * BK + ((kq ^ sw) << 3)];
#pragma unroll
            for (int mi = 0; mi < 4; mi++)
#pragma unroll
                for (int ni = 0; ni < 4; ni++)
                    acc[mi][ni] = __builtin_amdgcn_mfma_f32_16x16x32_bf16(
                        aF[mi], bF[ni], acc[mi][ni], 0, 0, 0);
        }
        __syncthreads();
    }
    // C/D: col = lane&15, row = (lane>>4)*4 + reg
    const int rq = (lane >> 4) * 4, cq = lane & 15;
    const int obase = off[e] + m0;
#pragma unroll
    for (int mi = 0; mi < 4; mi++) {
#pragma unroll
        for (int reg = 0; reg < 4; reg++) {
            const int rl = wm + mi * 16 + rq + reg;
            int ci = m0 + rl; if (ci >= ce) ci = ce - 1;
            const int tok = list[e * T_ + ci];
            const float pv = probs[(size_t)tok * E_ + e];
#pragma unroll
            for (int ni = 0; ni < 4; ni++) {
                const int col = n0 + wn + ni * 16 + cq;
                const float v = acc[mi][ni][reg];
                // tanh-gelu via sigmoid: 0.5(1+tanh(u)) = sigma(2u); max dev vs erf-gelu ~3e-3
                const float u = 0.7978845608028654f * v * (1.0f + 0.044715f * v * v);
                const float g = v / (1.0f + __expf(-2.0f * u));
                Ag[(size_t)(obase + rl) * F_ + col] = __float2bfloat16(g * pv);
            }
        }
    }
}

// GEMM2 (gathered, split-K=2, no atomics): Y[kh][off[e]+i][h] = (Ag_e @ W2_e)[i][h] over k-half
__global__ __launch_bounds__(256)
void gemm2_kernel(const __hip_bfloat16* __restrict__ Ag,
                  const __hip_bfloat16* __restrict__ W2t,
                  const int* __restrict__ cnt, const int* __restrict__ off,
                  __hip_bfloat16* __restrict__ Y) {
    const int e  = blockIdx.z >> 1, kh = blockIdx.z & 1;
    const int ce = cnt[e];
    const int m0 = blockIdx.y * BM;
    if (m0 >= ce) return;
    const int n0 = blockIdx.x * BN;   // over H
    const int oe = off[e];
    __shared__ __align__(16) __hip_bfloat16 As[BM * BK];
    __shared__ __align__(16) __hip_bfloat16 Bs[BN * BK];
    const int tid = threadIdx.x, lane = tid & 63, wave = tid >> 6;
    const int wm = (wave >> 1) * 64, wn = (wave & 1) * 64;
    const int lr  = lane >> 3;
    const int lcg = ((lane & 7) ^ lr) * 8;
    const __hip_bfloat16* Abase = Ag + (size_t)oe * F_ + kh * (F_ / 2);
    const __hip_bfloat16* Bbase = W2t + (size_t)e * F_ + kh * (F_ / 2);

    f32x4 acc[4][4];
#pragma unroll
    for (int mi = 0; mi < 4; mi++)
#pragma unroll
        for (int ni = 0; ni < 4; ni++) acc[mi][ni] = (f32x4){0.f, 0.f, 0.f, 0.f};

    for (int k0 = 0; k0 < F_ / 2; k0 += BK) {
#pragma unroll
        for (int j = 0; j < 4; j++) {
            const int i = wave * 4 + j;
            const int r = i * 8 + lr;
            async_copy16(Abase + (size_t)(m0 + r) * F_ + (k0 + lcg), (char*)As + i * 1024);
            async_copy16(Bbase + (size_t)(n0 + r) * EF_ + (k0 + lcg), (char*)Bs + i * 1024);
        }
        __syncthreads();
#pragma unroll
        for (int kt = 0; kt < BK / 32; kt++) {
            const int kq = kt * 4 + (lane >> 4);
            const int mr = lane & 15;
            const int sw = mr & 7;
            short8 aF[4], bF[4];
#pragma unroll
            for (int mi = 0; mi < 4; mi++)
                aF[mi] = *(const short8*)&As[(wm + mi * 16 + mr) * BK + ((kq ^ sw) << 3)];
#pragma unroll
            for (int ni = 0; ni < 4; ni++)
                bF[ni] = *(const short8*)&Bs[(wn + ni * 16 + mr) * BK + ((kq ^ sw) << 3)];
#pragma unroll
            for (int mi = 0; mi < 4; mi++)
#pragma unroll
                for (int ni = 0; ni < 4; ni++)
                    acc[mi][ni] = __builtin_amdgcn_mfma_f32_16x16x32_bf16(
                        aF[mi], bF[ni], acc[mi][ni], 0, 0, 0);
        }
        __syncthreads();
    }
    const int rq = (lane >> 4) * 4, cq = lane & 15;
    __hip_bfloat16* Yk = Y + (size_t)kh * ROWCAP * H_ + (size_t)(oe + m0) * H_;
#pragma unroll
    for (int mi = 0; mi < 4; mi++)
#pragma unroll
        for (int reg = 0; reg < 4; reg++) {
            const int rl = wm + mi * 16 + rq + reg;
#pragma unroll
            for (int ni = 0; ni < 4; ni++) {
                const int col = n0 + wn + ni * 16 + cq;
                Yk[(size_t)rl * H_ + col] = __float2bfloat16(acc[mi][ni][reg]);
            }
        }
}

// out[t][h] = res[t][h] + sum_{e routed} (Y0 + Y1)[off[e]+slot[t][e]][h]
__global__ __launch_bounds__(256)
void combine_kernel(const float* __restrict__ res, const float* __restrict__ probs,
                    const int* __restrict__ off, const int* __restrict__ slot,
                    const __hip_bfloat16* __restrict__ Y, float* __restrict__ out) {
    const int idx = blockIdx.x * 256 + threadIdx.x;   // T_*(H_/4) threads
    const int t  = idx >> 8;
    const int hc = (idx & 255) * 4;
    const float4 r = ((const float4*)res)[idx];
    float s0 = r.x, s1 = r.y, s2 = r.z, s3 = r.w;
#pragma unroll
    for (int e = 0; e < E_; e++) {
        if (probs[(size_t)t * E_ + e] > 0.0f) {
            const int row = off[e] + slot[(size_t)t * E_ + e];
            const ushort4 y0 = *(const ushort4*)&Y[(size_t)row * H_ + hc];
            const ushort4 y1 = *(const ushort4*)&Y[((size_t)ROWCAP + row) * H_ + hc];
            s0 += bf2f(y0.x) + bf2f(y1.x);
            s1 += bf2f(y0.y) + bf2f(y1.y);
            s2 += bf2f(y0.z) + bf2f(y1.z);
            s3 += bf2f(y0.w) + bf2f(y1.w);
        }
    }
    ((float4*)out)[idx] = make_float4(s0, s1, s2, s3);
}

extern "C" void kernel_launch(void* const* d_in, const int* in_sizes, int n_in,
                              void* d_out, int out_size, void* d_ws, size_t ws_size,
                              hipStream_t stream) {
    const float* x     = (const float*)d_in[0];
    const float* res   = (const float*)d_in[1];
    const float* probs = (const float*)d_in[2];
    const float* w1    = (const float*)d_in[4];
    const float* w2    = (const float*)d_in[5];
    float* out = (float*)d_out;

    char* ws = (char*)d_ws;
    __hip_bfloat16* Xb  = (__hip_bfloat16*)(ws);                 // 4 MB
    __hip_bfloat16* W1t = (__hip_bfloat16*)(ws + (4ull  << 20)); // 32 MB
    __hip_bfloat16* W2t = (__hip_bfloat16*)(ws + (36ull << 20)); // 32 MB
    __hip_bfloat16* Ag  = (__hip_bfloat16*)(ws + (68ull << 20)); // ROWCAP*F*2 = 36 MB
    __hip_bfloat16* Y   = (__hip_bfloat16*)(ws + (106ull << 20));// 2*ROWCAP*H*2 = 18 MB
    char* meta = ws + (125ull << 20);
    int* cnt  = (int*)meta;                       // 4 ints
    int* off  = (int*)(meta + 64);                // 5 ints
    int* list = (int*)(meta + 256);               // E*T ints = 32 KB
    int* slot = (int*)(meta + 256 + 4 * T_ * 4);  // T*E ints = 32 KB

    hipMemsetAsync(cnt, 0, E_ * sizeof(int), stream);
    convert_x_kernel<<<dim3(T_ * H_ / 256), dim3(256), 0, stream>>>(x, Xb);
    trans_w1_kernel<<<dim3(F_ / 32, H_ / 32, E_), dim3(32, 8), 0, stream>>>(w1, W1t);
    trans_w2_kernel<<<dim3(H_ / 32, F_ / 32, E_), dim3(32, 8), 0, stream>>>(w2, W2t);
    build_lists_kernel<<<dim3(T_ / 256), dim3(256), 0, stream>>>(probs, cnt, list, slot);
    prefix_kernel<<<dim3(1), dim3(64), 0, stream>>>(cnt, off);
    gemm1_kernel<<<dim3(F_ / BN, T_ / BM, E_), dim3(256), 0, stream>>>(
        Xb, W1t, probs, cnt, off, list, Ag);
    gemm2_kernel<<<dim3(H_ / BN, T_ / BM, 2 * E_), dim3(256), 0, stream>>>(
        Ag, W2t, cnt, off, Y);
    combine_kernel<<<dim3(T_ * (H_ / 4) / 256), dim3(256), 0, stream>>>(
        res, probs, off, slot, Y, out);
}

// Round 5
// 326.923 us; speedup vs baseline: 1.2854x; 1.0379x over previous
//
#include <hip/hip_runtime.h>
#include <hip/hip_bf16.h>
#include <math.h>

// Problem constants (S=1024, B=2 -> T=2048)
#define T_  2048
#define H_  1024
#define F_  4096
#define E_  4
#define EF_ (E_*F_)
#define ROWCAP 4608   // sum_e ceil(cnt_e/128)*128 <= 4096 + 4*127 = 4604
#define KSPLIT 4      // gemm2 split-K slices (parallelism: ~512 -> ~1024 blocks)
#define KS (F_/KSPLIT)

typedef __attribute__((ext_vector_type(8))) short short8;   // 8 bf16 = 4 VGPRs
typedef __attribute__((ext_vector_type(4))) float f32x4;    // MFMA 16x16 accumulator

#define BM 128
#define BN 128
#define BK 64

__device__ __forceinline__ void async_copy16(const void* g, void* l) {
    __builtin_amdgcn_global_load_lds(
        (const __attribute__((address_space(1))) void*)g,
        (__attribute__((address_space(3))) void*)l, 16, 0, 0);
}

__device__ __forceinline__ float bf2f(unsigned short u) {
    return __uint_as_float(((unsigned)u) << 16);
}

__global__ __launch_bounds__(256)
void convert_x_kernel(const float* __restrict__ x, __hip_bfloat16* __restrict__ xb) {
    int i = blockIdx.x * 256 + threadIdx.x;
    xb[i] = __float2bfloat16(x[i]);
}

// w1 [E][H][F] fp32 -> w1t [E][F][H] bf16 (B^T for GEMM1)
__global__ __launch_bounds__(256)
void trans_w1_kernel(const float* __restrict__ w1, __hip_bfloat16* __restrict__ w1t) {
    __shared__ float tile[32][33];
    const int e = blockIdx.z;
    const int f0 = blockIdx.x * 32, h0 = blockIdx.y * 32;
    const float* src = w1 + (size_t)e * H_ * F_;
    __hip_bfloat16* dst = w1t + (size_t)e * F_ * H_;
    const int tx = threadIdx.x, ty = threadIdx.y;
#pragma unroll
    for (int i = 0; i < 32; i += 8)
        tile[ty + i][tx] = src[(size_t)(h0 + ty + i) * F_ + f0 + tx];
    __syncthreads();
#pragma unroll
    for (int i = 0; i < 32; i += 8)
        dst[(size_t)(f0 + ty + i) * H_ + h0 + tx] = __float2bfloat16(tile[tx][ty + i]);
}

// w2 [E][F][H] fp32 -> w2t [H][E*F] bf16 (B^T for GEMM2)
__global__ __launch_bounds__(256)
void trans_w2_kernel(const float* __restrict__ w2, __hip_bfloat16* __restrict__ w2t) {
    __shared__ float tile[32][33];
    const int e = blockIdx.z;
    const int h0 = blockIdx.x * 32, f0 = blockIdx.y * 32;
    const float* src = w2 + (size_t)e * F_ * H_;
    const int tx = threadIdx.x, ty = threadIdx.y;
#pragma unroll
    for (int i = 0; i < 32; i += 8)
        tile[ty + i][tx] = src[(size_t)(f0 + ty + i) * H_ + h0 + tx];
    __syncthreads();
#pragma unroll
    for (int i = 0; i < 32; i += 8)
        w2t[(size_t)(h0 + ty + i) * EF_ + (size_t)e * F_ + f0 + tx] =
            __float2bfloat16(tile[tx][ty + i]);
}

// Routing: probs>0 iff routed (probs is masked-renormalized softmax; exactly TOPK=2/token).
__global__ __launch_bounds__(256)
void build_lists_kernel(const float* __restrict__ probs, int* __restrict__ cnt,
                        int* __restrict__ list, int* __restrict__ slot) {
    int t = blockIdx.x * 256 + threadIdx.x;
#pragma unroll
    for (int e = 0; e < E_; e++) {
        if (probs[t * E_ + e] > 0.0f) {
            int pos = atomicAdd(&cnt[e], 1);
            list[e * T_ + pos] = t;
            slot[t * E_ + e] = pos;
        }
    }
}

__global__ void prefix_kernel(const int* __restrict__ cnt, int* __restrict__ off) {
    if (threadIdx.x == 0) {
        int acc = 0;
#pragma unroll
        for (int e = 0; e < E_; e++) { off[e] = acc; acc += (cnt[e] + 127) & ~127; }
        off[E_] = acc;
    }
}

// LDS swizzle: row r chunk c stored at c ^ (r&7); staging fetches the permuted global
// chunk per lane; readers XOR. Conflict-free (verified R2: 2.5e7 -> 0).

// GEMM1 (gathered): Ag[off[e]+i][f] = bf16( p * gelu( (X[list[e][i]] @ W1_e)[f] ) )
__global__ __launch_bounds__(256)
void gemm1_kernel(const __hip_bfloat16* __restrict__ Xb,
                  const __hip_bfloat16* __restrict__ W1t,
                  const float* __restrict__ probs,
                  const int* __restrict__ cnt, const int* __restrict__ off,
                  const int* __restrict__ list,
                  __hip_bfloat16* __restrict__ Ag) {
    const int e  = blockIdx.z;
    const int ce = cnt[e];
    const int m0 = blockIdx.y * BM;
    if (m0 >= ce) return;
    const int n0 = blockIdx.x * BN;   // over F
    const __hip_bfloat16* Bt = W1t + (size_t)e * F_ * H_;
    __shared__ __align__(16) __hip_bfloat16 As[BM * BK];
    __shared__ __align__(16) __hip_bfloat16 Bs[BN * BK];
    const int tid = threadIdx.x, lane = tid & 63, wave = tid >> 6;
    const int wm = (wave >> 1) * 64, wn = (wave & 1) * 64;
    const int lr  = lane >> 3;
    const int lcg = ((lane & 7) ^ lr) * 8;

    int tokA[4];
#pragma unroll
    for (int j = 0; j < 4; j++) {
        int idx = m0 + (wave * 4 + j) * 8 + lr;
        if (idx >= ce) idx = ce - 1;          // clamp: dup row, store discarded below
        tokA[j] = list[e * T_ + idx];
    }

    f32x4 acc[4][4];
#pragma unroll
    for (int mi = 0; mi < 4; mi++)
#pragma unroll
        for (int ni = 0; ni < 4; ni++) acc[mi][ni] = (f32x4){0.f, 0.f, 0.f, 0.f};

    for (int k0 = 0; k0 < H_; k0 += BK) {
#pragma unroll
        for (int j = 0; j < 4; j++) {
            const int i = wave * 4 + j;
            const int r = i * 8 + lr;
            async_copy16(Xb + (size_t)tokA[j] * H_ + (k0 + lcg), (char*)As + i * 1024);
            async_copy16(Bt + (size_t)(n0 + r) * H_ + (k0 + lcg), (char*)Bs + i * 1024);
        }
        __syncthreads();
#pragma unroll
        for (int kt = 0; kt < BK / 32; kt++) {
            const int kq = kt * 4 + (lane >> 4);
            const int mr = lane & 15;
            const int sw = mr & 7;
            short8 aF[4], bF[4];
#pragma unroll
            for (int mi = 0; mi < 4; mi++)
                aF[mi] = *(const short8*)&As[(wm + mi * 16 + mr) * BK + ((kq ^ sw) << 3)];
#pragma unroll
            for (int ni = 0; ni < 4; ni++)
                bF[ni] = *(const short8*)&Bs[(wn + ni * 16 + mr) * BK + ((kq ^ sw) << 3)];
#pragma unroll
            for (int mi = 0; mi < 4; mi++)
#pragma unroll
                for (int ni = 0; ni < 4; ni++)
                    acc[mi][ni] = __builtin_amdgcn_mfma_f32_16x16x32_bf16(
                        aF[mi], bF[ni], acc[mi][ni], 0, 0, 0);
        }
        __syncthreads();
    }
    // C/D: col = lane&15, row = (lane>>4)*4 + reg
    const int rq = (lane >> 4) * 4, cq = lane & 15;
    const int obase = off[e] + m0;
#pragma unroll
    for (int mi = 0; mi < 4; mi++) {
#pragma unroll
        for (int reg = 0; reg < 4; reg++) {
            const int rl = wm + mi * 16 + rq + reg;
            int ci = m0 + rl; if (ci >= ce) ci = ce - 1;
            const int tok = list[e * T_ + ci];
            const float pv = probs[(size_t)tok * E_ + e];
#pragma unroll
            for (int ni = 0; ni < 4; ni++) {
                const int col = n0 + wn + ni * 16 + cq;
                const float v = acc[mi][ni][reg];
                // tanh-gelu via sigmoid: 0.5(1+tanh(u)) = sigma(2u); max dev vs erf-gelu ~3e-3
                const float u = 0.7978845608028654f * v * (1.0f + 0.044715f * v * v);
                const float g = v / (1.0f + __expf(-2.0f * u));
                Ag[(size_t)(obase + rl) * F_ + col] = __float2bfloat16(g * pv);
            }
        }
    }
}

// GEMM2 (gathered, split-K=KSPLIT, no atomics):
// Y[ks][off[e]+i][h] = (Ag_e @ W2_e)[i][h] over k in [ks*KS,(ks+1)*KS)
__global__ __launch_bounds__(256)
void gemm2_kernel(const __hip_bfloat16* __restrict__ Ag,
                  const __hip_bfloat16* __restrict__ W2t,
                  const int* __restrict__ cnt, const int* __restrict__ off,
                  __hip_bfloat16* __restrict__ Y) {
    const int e  = blockIdx.z >> 2, kh = blockIdx.z & 3;
    const int ce = cnt[e];
    const int m0 = blockIdx.y * BM;
    if (m0 >= ce) return;
    const int n0 = blockIdx.x * BN;   // over H
    const int oe = off[e];
    __shared__ __align__(16) __hip_bfloat16 As[BM * BK];
    __shared__ __align__(16) __hip_bfloat16 Bs[BN * BK];
    const int tid = threadIdx.x, lane = tid & 63, wave = tid >> 6;
    const int wm = (wave >> 1) * 64, wn = (wave & 1) * 64;
    const int lr  = lane >> 3;
    const int lcg = ((lane & 7) ^ lr) * 8;
    const __hip_bfloat16* Abase = Ag + (size_t)oe * F_ + kh * KS;
    const __hip_bfloat16* Bbase = W2t + (size_t)e * F_ + kh * KS;

    f32x4 acc[4][4];
#pragma unroll
    for (int mi = 0; mi < 4; mi++)
#pragma unroll
        for (int ni = 0; ni < 4; ni++) acc[mi][ni] = (f32x4){0.f, 0.f, 0.f, 0.f};

    for (int k0 = 0; k0 < KS; k0 += BK) {
#pragma unroll
        for (int j = 0; j < 4; j++) {
            const int i = wave * 4 + j;
            const int r = i * 8 + lr;
            async_copy16(Abase + (size_t)(m0 + r) * F_ + (k0 + lcg), (char*)As + i * 1024);
            async_copy16(Bbase + (size_t)(n0 + r) * EF_ + (k0 + lcg), (char*)Bs + i * 1024);
        }
        __syncthreads();
#pragma unroll
        for (int kt = 0; kt < BK / 32; kt++) {
            const int kq = kt * 4 + (lane >> 4);
            const int mr = lane & 15;
            const int sw = mr & 7;
            short8 aF[4], bF[4];
#pragma unroll
            for (int mi = 0; mi < 4; mi++)
                aF[mi] = *(const short8*)&As[(wm + mi * 16 + mr) * BK + ((kq ^ sw) << 3)];
#pragma unroll
            for (int ni = 0; ni < 4; ni++)
                bF[ni] = *(const short8*)&Bs[(wn + ni * 16 + mr) * BK + ((kq ^ sw) << 3)];
#pragma unroll
            for (int mi = 0; mi < 4; mi++)
#pragma unroll
                for (int ni = 0; ni < 4; ni++)
                    acc[mi][ni] = __builtin_amdgcn_mfma_f32_16x16x32_bf16(
                        aF[mi], bF[ni], acc[mi][ni], 0, 0, 0);
        }
        __syncthreads();
    }
    const int rq = (lane >> 4) * 4, cq = lane & 15;
    __hip_bfloat16* Yk = Y + (size_t)kh * ROWCAP * H_ + (size_t)(oe + m0) * H_;
#pragma unroll
    for (int mi = 0; mi < 4; mi++)
#pragma unroll
        for (int reg = 0; reg < 4; reg++) {
            const int rl = wm + mi * 16 + rq + reg;
#pragma unroll
            for (int ni = 0; ni < 4; ni++) {
                const int col = n0 + wn + ni * 16 + cq;
                Yk[(size_t)rl * H_ + col] = __float2bfloat16(acc[mi][ni][reg]);
            }
        }
}

// out[t][h] = res[t][h] + sum_{e routed} sum_{ks} Y[ks][off[e]+slot[t][e]][h]
__global__ __launch_bounds__(256)
void combine_kernel(const float* __restrict__ res, const float* __restrict__ probs,
                    const int* __restrict__ off, const int* __restrict__ slot,
                    const __hip_bfloat16* __restrict__ Y, float* __restrict__ out) {
    const int idx = blockIdx.x * 256 + threadIdx.x;   // T_*(H_/4) threads
    const int t  = idx >> 8;
    const int hc = (idx & 255) * 4;
    const float4 r = ((const float4*)res)[idx];
    float s0 = r.x, s1 = r.y, s2 = r.z, s3 = r.w;
#pragma unroll
    for (int e = 0; e < E_; e++) {
        if (probs[(size_t)t * E_ + e] > 0.0f) {
            const int row = off[e] + slot[(size_t)t * E_ + e];
#pragma unroll
            for (int ks = 0; ks < KSPLIT; ks++) {
                const ushort4 y = *(const ushort4*)&Y[((size_t)ks * ROWCAP + row) * H_ + hc];
                s0 += bf2f(y.x); s1 += bf2f(y.y); s2 += bf2f(y.z); s3 += bf2f(y.w);
            }
        }
    }
    ((float4*)out)[idx] = make_float4(s0, s1, s2, s3);
}

extern "C" void kernel_launch(void* const* d_in, const int* in_sizes, int n_in,
                              void* d_out, int out_size, void* d_ws, size_t ws_size,
                              hipStream_t stream) {
    const float* x     = (const float*)d_in[0];
    const float* res   = (const float*)d_in[1];
    const float* probs = (const float*)d_in[2];
    const float* w1    = (const float*)d_in[4];
    const float* w2    = (const float*)d_in[5];
    float* out = (float*)d_out;

    char* ws = (char*)d_ws;
    // Y (36 MiB) ALIASES Xb+W1t: both are dead after gemm1, and gemm2 (writes Y)
    // runs after gemm1 in stream order. Every call rewrites Xb/W1t before gemm1.
    __hip_bfloat16* Y   = (__hip_bfloat16*)(ws);                 // 36 MiB (KSPLIT slices)
    __hip_bfloat16* Xb  = (__hip_bfloat16*)(ws);                 //  4 MiB (dead after gemm1)
    __hip_bfloat16* W1t = (__hip_bfloat16*)(ws + (4ull  << 20)); // 32 MiB (dead after gemm1)
    __hip_bfloat16* W2t = (__hip_bfloat16*)(ws + (36ull << 20)); // 32 MiB
    __hip_bfloat16* Ag  = (__hip_bfloat16*)(ws + (68ull << 20)); // 36 MiB
    char* meta = ws + (104ull << 20);
    int* cnt  = (int*)meta;                       // 4 ints
    int* off  = (int*)(meta + 64);                // 5 ints
    int* list = (int*)(meta + 256);               // E*T ints = 32 KB
    int* slot = (int*)(meta + 256 + 4 * T_ * 4);  // T*E ints = 32 KB

    hipMemsetAsync(cnt, 0, E_ * sizeof(int), stream);
    convert_x_kernel<<<dim3(T_ * H_ / 256), dim3(256), 0, stream>>>(x, Xb);
    trans_w1_kernel<<<dim3(F_ / 32, H_ / 32, E_), dim3(32, 8), 0, stream>>>(w1, W1t);
    trans_w2_kernel<<<dim3(H_ / 32, F_ / 32, E_), dim3(32, 8), 0, stream>>>(w2, W2t);
    build_lists_kernel<<<dim3(T_ / 256), dim3(256), 0, stream>>>(probs, cnt, list, slot);
    prefix_kernel<<<dim3(1), dim3(64), 0, stream>>>(cnt, off);
    gemm1_kernel<<<dim3(F_ / BN, T_ / BM, E_), dim3(256), 0, stream>>>(
        Xb, W1t, probs, cnt, off, list, Ag);
    gemm2_kernel<<<dim3(H_ / BN, T_ / BM, KSPLIT * E_), dim3(256), 0, stream>>>(
        Ag, W2t, cnt, off, Y);
    combine_kernel<<<dim3(T_ * (H_ / 4) / 256), dim3(256), 0, stream>>>(
        res, probs, off, slot, Y, out);
}

// Round 6
// 322.006 us; speedup vs baseline: 1.3050x; 1.0153x over previous
//
#include <hip/hip_runtime.h>
#include <hip/hip_bf16.h>
#include <math.h>

// Problem constants (S=1024, B=2 -> T=2048)
#define T_  2048
#define H_  1024
#define F_  4096
#define E_  4
#define EF_ (E_*F_)
#define ROWCAP 4608   // sum_e ceil(cnt_e/128)*128 <= 4096 + 4*127 = 4604
#define KSPLIT 4      // gemm2 split-K slices
#define KS (F_/KSPLIT)

typedef __attribute__((ext_vector_type(8))) short short8;   // 8 bf16 = 4 VGPRs
typedef __attribute__((ext_vector_type(4))) float f32x4;    // MFMA 16x16 accumulator

#define BM 128
#define BN 128
#define BK 64

__device__ __forceinline__ void async_copy16(const void* g, void* l) {
    __builtin_amdgcn_global_load_lds(
        (const __attribute__((address_space(1))) void*)g,
        (__attribute__((address_space(3))) void*)l, 16, 0, 0);
}

__device__ __forceinline__ float bf2f(unsigned short u) {
    return __uint_as_float(((unsigned)u) << 16);
}
__device__ __forceinline__ short f2bf_bits(float f) {
    __hip_bfloat16 b = __float2bfloat16(f);
    return *(short*)&b;
}

__global__ __launch_bounds__(256)
void convert_x_kernel(const float* __restrict__ x, __hip_bfloat16* __restrict__ xb) {
    int i = blockIdx.x * 256 + threadIdx.x;
    xb[i] = __float2bfloat16(x[i]);
}

// Fused fast transpose+convert: z<4 -> W1 expert z ([H][F] fp32 -> w1t[e][f][h] bf16);
// z>=4 -> W2 expert z-4 ([F][H] fp32 -> w2t[h][e*F+f] bf16).
// 64x64 tile; float4 loads (16B/lane); LDS stride-69 transpose (both phases measured
// <=2 lanes/bank by construction); ushort8 stores (16B/lane).
__global__ __launch_bounds__(256)
void trans_kernel(const float* __restrict__ w1, const float* __restrict__ w2,
                  __hip_bfloat16* __restrict__ w1t, __hip_bfloat16* __restrict__ w2t) {
    __shared__ float tile[64 * 69 + 4];   // tile[c][r] at c*69 + r (transposed at write)
    const int z = blockIdx.z;
    const float* src;
    __hip_bfloat16* dst;
    int r0, c0, C, dstStride;
    if (z < E_) {
        src = w1 + (size_t)z * H_ * F_;
        dst = w1t + (size_t)z * F_ * H_;
        C = F_; dstStride = H_;
        r0 = blockIdx.y * 64;   // over H (16 tiles)
        c0 = blockIdx.x * 64;   // over F (64 tiles)
    } else {
        const int e = z - E_;
        src = w2 + (size_t)e * F_ * H_;
        dst = w2t + (size_t)e * F_;     // element (r=f,c=h) -> dst[c*EF_ + r]
        C = H_; dstStride = EF_;
        r0 = blockIdx.x * 64;   // over F (64 tiles)
        c0 = blockIdx.y * 64;   // over H (16 tiles)
    }
    const int t = threadIdx.x;
    const int cl = (t & 15) * 4;          // tile col of this thread's float4
#pragma unroll
    for (int p = 0; p < 4; p++) {
        const int rl = (t >> 4) + 16 * p; // tile row
        const float4 v = *(const float4*)&src[(size_t)(r0 + rl) * C + (c0 + cl)];
        tile[(cl + 0) * 69 + rl] = v.x;
        tile[(cl + 1) * 69 + rl] = v.y;
        tile[(cl + 2) * 69 + rl] = v.z;
        tile[(cl + 3) * 69 + rl] = v.w;
    }
    __syncthreads();
    const int orow = (t & 7) * 8;         // 8 consecutive source-rows -> output cols
#pragma unroll
    for (int q = 0; q < 2; q++) {
        const int oc = (t >> 3) + 32 * q; // output row (= source col)
        short8 pk;
#pragma unroll
        for (int j = 0; j < 8; j++)
            pk[j] = f2bf_bits(tile[oc * 69 + orow + j]);
        *(short8*)&((short*)dst)[(size_t)(c0 + oc) * dstStride + r0 + orow] = pk;
    }
}

// Routing: probs>0 iff routed (probs is masked-renormalized softmax; exactly TOPK=2/token).
__global__ __launch_bounds__(256)
void build_lists_kernel(const float* __restrict__ probs, int* __restrict__ cnt,
                        int* __restrict__ list, int* __restrict__ slot) {
    int t = blockIdx.x * 256 + threadIdx.x;
#pragma unroll
    for (int e = 0; e < E_; e++) {
        if (probs[t * E_ + e] > 0.0f) {
            int pos = atomicAdd(&cnt[e], 1);
            list[e * T_ + pos] = t;
            slot[t * E_ + e] = pos;
        }
    }
}

__global__ void prefix_kernel(const int* __restrict__ cnt, int* __restrict__ off) {
    if (threadIdx.x == 0) {
        int acc = 0;
#pragma unroll
        for (int e = 0; e < E_; e++) { off[e] = acc; acc += (cnt[e] + 127) & ~127; }
        off[E_] = acc;
    }
}

// LDS swizzle: row r chunk c stored at c ^ (r&7); staging fetches the permuted global
// chunk per lane; readers XOR. Conflict-free (verified R2: 2.5e7 -> 0).

// GEMM1 (gathered): Ag[off[e]+i][f] = bf16( p * gelu( (X[list[e][i]] @ W1_e)[f] ) )
__global__ __launch_bounds__(256)
void gemm1_kernel(const __hip_bfloat16* __restrict__ Xb,
                  const __hip_bfloat16* __restrict__ W1t,
                  const float* __restrict__ probs,
                  const int* __restrict__ cnt, const int* __restrict__ off,
                  const int* __restrict__ list,
                  __hip_bfloat16* __restrict__ Ag) {
    const int e  = blockIdx.z;
    const int ce = cnt[e];
    const int m0 = blockIdx.y * BM;
    if (m0 >= ce) return;
    const int n0 = blockIdx.x * BN;   // over F
    const __hip_bfloat16* Bt = W1t + (size_t)e * F_ * H_;
    __shared__ __align__(16) __hip_bfloat16 As[BM * BK];
    __shared__ __align__(16) __hip_bfloat16 Bs[BN * BK];
    const int tid = threadIdx.x, lane = tid & 63, wave = tid >> 6;
    const int wm = (wave >> 1) * 64, wn = (wave & 1) * 64;
    const int lr  = lane >> 3;
    const int lcg = ((lane & 7) ^ lr) * 8;

    int tokA[4];
#pragma unroll
    for (int j = 0; j < 4; j++) {
        int idx = m0 + (wave * 4 + j) * 8 + lr;
        if (idx >= ce) idx = ce - 1;          // clamp: dup row, store discarded below
        tokA[j] = list[e * T_ + idx];
    }

    f32x4 acc[4][4];
#pragma unroll
    for (int mi = 0; mi < 4; mi++)
#pragma unroll
        for (int ni = 0; ni < 4; ni++) acc[mi][ni] = (f32x4){0.f, 0.f, 0.f, 0.f};

    for (int k0 = 0; k0 < H_; k0 += BK) {
#pragma unroll
        for (int j = 0; j < 4; j++) {
            const int i = wave * 4 + j;
            const int r = i * 8 + lr;
            async_copy16(Xb + (size_t)tokA[j] * H_ + (k0 + lcg), (char*)As + i * 1024);
            async_copy16(Bt + (size_t)(n0 + r) * H_ + (k0 + lcg), (char*)Bs + i * 1024);
        }
        __syncthreads();
#pragma unroll
        for (int kt = 0; kt < BK / 32; kt++) {
            const int kq = kt * 4 + (lane >> 4);
            const int mr = lane & 15;
            const int sw = mr & 7;
            short8 aF[4], bF[4];
#pragma unroll
            for (int mi = 0; mi < 4; mi++)
                aF[mi] = *(const short8*)&As[(wm + mi * 16 + mr) * BK + ((kq ^ sw) << 3)];
#pragma unroll
            for (int ni = 0; ni < 4; ni++)
                bF[ni] = *(const short8*)&Bs[(wn + ni * 16 + mr) * BK + ((kq ^ sw) << 3)];
#pragma unroll
            for (int mi = 0; mi < 4; mi++)
#pragma unroll
                for (int ni = 0; ni < 4; ni++)
                    acc[mi][ni] = __builtin_amdgcn_mfma_f32_16x16x32_bf16(
                        aF[mi], bF[ni], acc[mi][ni], 0, 0, 0);
        }
        __syncthreads();
    }
    // C/D: col = lane&15, row = (lane>>4)*4 + reg
    const int rq = (lane >> 4) * 4, cq = lane & 15;
    const int obase = off[e] + m0;
#pragma unroll
    for (int mi = 0; mi < 4; mi++) {
#pragma unroll
        for (int reg = 0; reg < 4; reg++) {
            const int rl = wm + mi * 16 + rq + reg;
            int ci = m0 + rl; if (ci >= ce) ci = ce - 1;
            const int tok = list[e * T_ + ci];
            const float pv = probs[(size_t)tok * E_ + e];
#pragma unroll
            for (int ni = 0; ni < 4; ni++) {
                const int col = n0 + wn + ni * 16 + cq;
                const float v = acc[mi][ni][reg];
                // tanh-gelu via sigmoid: 0.5(1+tanh(u)) = sigma(2u); max dev vs erf-gelu ~3e-3
                const float u = 0.7978845608028654f * v * (1.0f + 0.044715f * v * v);
                const float g = v / (1.0f + __expf(-2.0f * u));
                Ag[(size_t)(obase + rl) * F_ + col] = __float2bfloat16(g * pv);
            }
        }
    }
}

// GEMM2 (gathered, split-K=KSPLIT, no atomics):
// Y[ks][off[e]+i][h] = (Ag_e @ W2_e)[i][h] over k in [ks*KS,(ks+1)*KS)
__global__ __launch_bounds__(256)
void gemm2_kernel(const __hip_bfloat16* __restrict__ Ag,
                  const __hip_bfloat16* __restrict__ W2t,
                  const int* __restrict__ cnt, const int* __restrict__ off,
                  __hip_bfloat16* __restrict__ Y) {
    const int e  = blockIdx.z >> 2, kh = blockIdx.z & 3;
    const int ce = cnt[e];
    const int m0 = blockIdx.y * BM;
    if (m0 >= ce) return;
    const int n0 = blockIdx.x * BN;   // over H
    const int oe = off[e];
    __shared__ __align__(16) __hip_bfloat16 As[BM * BK];
    __shared__ __align__(16) __hip_bfloat16 Bs[BN * BK];
    const int tid = threadIdx.x, lane = tid & 63, wave = tid >> 6;
    const int wm = (wave >> 1) * 64, wn = (wave & 1) * 64;
    const int lr  = lane >> 3;
    const int lcg = ((lane & 7) ^ lr) * 8;
    const __hip_bfloat16* Abase = Ag + (size_t)oe * F_ + kh * KS;
    const __hip_bfloat16* Bbase = W2t + (size_t)e * F_ + kh * KS;

    f32x4 acc[4][4];
#pragma unroll
    for (int mi = 0; mi < 4; mi++)
#pragma unroll
        for (int ni = 0; ni < 4; ni++) acc[mi][ni] = (f32x4){0.f, 0.f, 0.f, 0.f};

    for (int k0 = 0; k0 < KS; k0 += BK) {
#pragma unroll
        for (int j = 0; j < 4; j++) {
            const int i = wave * 4 + j;
            const int r = i * 8 + lr;
            async_copy16(Abase + (size_t)(m0 + r) * F_ + (k0 + lcg), (char*)As + i * 1024);
            async_copy16(Bbase + (size_t)(n0 + r) * EF_ + (k0 + lcg), (char*)Bs + i * 1024);
        }
        __syncthreads();
#pragma unroll
        for (int kt = 0; kt < BK / 32; kt++) {
            const int kq = kt * 4 + (lane >> 4);
            const int mr = lane & 15;
            const int sw = mr & 7;
            short8 aF[4], bF[4];
#pragma unroll
            for (int mi = 0; mi < 4; mi++)
                aF[mi] = *(const short8*)&As[(wm + mi * 16 + mr) * BK + ((kq ^ sw) << 3)];
#pragma unroll
            for (int ni = 0; ni < 4; ni++)
                bF[ni] = *(const short8*)&Bs[(wn + ni * 16 + mr) * BK + ((kq ^ sw) << 3)];
#pragma unroll
            for (int mi = 0; mi < 4; mi++)
#pragma unroll
                for (int ni = 0; ni < 4; ni++)
                    acc[mi][ni] = __builtin_amdgcn_mfma_f32_16x16x32_bf16(
                        aF[mi], bF[ni], acc[mi][ni], 0, 0, 0);
        }
        __syncthreads();
    }
    const int rq = (lane >> 4) * 4, cq = lane & 15;
    __hip_bfloat16* Yk = Y + (size_t)kh * ROWCAP * H_ + (size_t)(oe + m0) * H_;
#pragma unroll
    for (int mi = 0; mi < 4; mi++)
#pragma unroll
        for (int reg = 0; reg < 4; reg++) {
            const int rl = wm + mi * 16 + rq + reg;
#pragma unroll
            for (int ni = 0; ni < 4; ni++) {
                const int col = n0 + wn + ni * 16 + cq;
                Yk[(size_t)rl * H_ + col] = __float2bfloat16(acc[mi][ni][reg]);
            }
        }
}

// out[t][h] = res[t][h] + sum_{e routed} sum_{ks} Y[ks][off[e]+slot[t][e]][h]
__global__ __launch_bounds__(256)
void combine_kernel(const float* __restrict__ res, const float* __restrict__ probs,
                    const int* __restrict__ off, const int* __restrict__ slot,
                    const __hip_bfloat16* __restrict__ Y, float* __restrict__ out) {
    const int idx = blockIdx.x * 256 + threadIdx.x;   // T_*(H_/4) threads
    const int t  = idx >> 8;
    const int hc = (idx & 255) * 4;
    const float4 r = ((const float4*)res)[idx];
    float s0 = r.x, s1 = r.y, s2 = r.z, s3 = r.w;
#pragma unroll
    for (int e = 0; e < E_; e++) {
        if (probs[(size_t)t * E_ + e] > 0.0f) {
            const int row = off[e] + slot[(size_t)t * E_ + e];
#pragma unroll
            for (int ks = 0; ks < KSPLIT; ks++) {
                const ushort4 y = *(const ushort4*)&Y[((size_t)ks * ROWCAP + row) * H_ + hc];
                s0 += bf2f(y.x); s1 += bf2f(y.y); s2 += bf2f(y.z); s3 += bf2f(y.w);
            }
        }
    }
    ((float4*)out)[idx] = make_float4(s0, s1, s2, s3);
}

extern "C" void kernel_launch(void* const* d_in, const int* in_sizes, int n_in,
                              void* d_out, int out_size, void* d_ws, size_t ws_size,
                              hipStream_t stream) {
    const float* x     = (const float*)d_in[0];
    const float* res   = (const float*)d_in[1];
    const float* probs = (const float*)d_in[2];
    const float* w1    = (const float*)d_in[4];
    const float* w2    = (const float*)d_in[5];
    float* out = (float*)d_out;

    char* ws = (char*)d_ws;
    // Y (36 MiB) ALIASES Xb+W1t: both are dead after gemm1, and gemm2 (writes Y)
    // runs after gemm1 in stream order. Every call rewrites Xb/W1t before gemm1.
    __hip_bfloat16* Y   = (__hip_bfloat16*)(ws);                 // 36 MiB (KSPLIT slices)
    __hip_bfloat16* Xb  = (__hip_bfloat16*)(ws);                 //  4 MiB (dead after gemm1)
    __hip_bfloat16* W1t = (__hip_bfloat16*)(ws + (4ull  << 20)); // 32 MiB (dead after gemm1)
    __hip_bfloat16* W2t = (__hip_bfloat16*)(ws + (36ull << 20)); // 32 MiB
    __hip_bfloat16* Ag  = (__hip_bfloat16*)(ws + (68ull << 20)); // 36 MiB
    char* meta = ws + (104ull << 20);
    int* cnt  = (int*)meta;                       // 4 ints
    int* off  = (int*)(meta + 64);                // 5 ints
    int* list = (int*)(meta + 256);               // E*T ints = 32 KB
    int* slot = (int*)(meta + 256 + 4 * T_ * 4);  // T*E ints = 32 KB

    hipMemsetAsync(cnt, 0, E_ * sizeof(int), stream);
    convert_x_kernel<<<dim3(T_ * H_ / 256), dim3(256), 0, stream>>>(x, Xb);
    trans_kernel<<<dim3(64, 16, 2 * E_), dim3(256), 0, stream>>>(w1, w2, W1t, W2t);
    build_lists_kernel<<<dim3(T_ / 256), dim3(256), 0, stream>>>(probs, cnt, list, slot);
    prefix_kernel<<<dim3(1), dim3(64), 0, stream>>>(cnt, off);
    gemm1_kernel<<<dim3(F_ / BN, T_ / BM, E_), dim3(256), 0, stream>>>(
        Xb, W1t, probs, cnt, off, list, Ag);
    gemm2_kernel<<<dim3(H_ / BN, T_ / BM, KSPLIT * E_), dim3(256), 0, stream>>>(
        Ag, W2t, cnt, off, Y);
    combine_kernel<<<dim3(T_ * (H_ / 4) / 256), dim3(256), 0, stream>>>(
        res, probs, off, slot, Y, out);
}

// Round 7
// 312.790 us; speedup vs baseline: 1.3435x; 1.0295x over previous
//
#include <hip/hip_runtime.h>
#include <hip/hip_bf16.h>
#include <math.h>

// Problem constants (S=1024, B=2 -> T=2048)
#define T_  2048
#define H_  1024
#define F_  4096
#define E_  4
#define EF_ (E_*F_)
#define ROWCAP 4608   // sum_e ceil(cnt_e/128)*128 <= 4096 + 4*127 = 4604
#define KSPLIT 4      // gemm2 split-K slices
#define KS (F_/KSPLIT)

typedef __attribute__((ext_vector_type(8))) short short8;   // 8 bf16 = 4 VGPRs
typedef __attribute__((ext_vector_type(4))) float f32x4;    // MFMA 16x16 accumulator

#define BM 128
#define BN 128
#define BK 64

__device__ __forceinline__ void async_copy16(const void* g, void* l) {
    __builtin_amdgcn_global_load_lds(
        (const __attribute__((address_space(1))) void*)g,
        (__attribute__((address_space(3))) void*)l, 16, 0, 0);
}

__device__ __forceinline__ float bf2f(unsigned short u) {
    return __uint_as_float(((unsigned)u) << 16);
}
__device__ __forceinline__ short f2bf_bits(float f) {
    __hip_bfloat16 b = __float2bfloat16(f);
    return *(short*)&b;
}

// ONE prep kernel, grid (64,16,9):
//   z<4 : W1 expert z   [H][F] fp32 -> w1t[e][f][h] bf16 (64x64 LDS transpose)
//   4<=z<8 : W2 expert z-4 [F][H] fp32 -> w2t[h][e*F+f] bf16
//   z==8: X copy-convert fp32->bf16 (1024 blocks x 2048 elems); block (0,0,8)
//         additionally builds the routing lists (ballot-aggregated, no global atomics).
__global__ __launch_bounds__(256)
void trans_kernel(const float* __restrict__ w1, const float* __restrict__ w2,
                  const float* __restrict__ x,  const float* __restrict__ probs,
                  __hip_bfloat16* __restrict__ w1t, __hip_bfloat16* __restrict__ w2t,
                  __hip_bfloat16* __restrict__ xb,
                  int* __restrict__ cnt_g, int* __restrict__ off_g,
                  int* __restrict__ list, int* __restrict__ slot) {
    const int z = blockIdx.z;
    const int t = threadIdx.x;

    if (z == 2 * E_) {
        // ---- X convert path ----
        const int bid = blockIdx.y * 64 + blockIdx.x;          // 0..1023
        const size_t base = ((size_t)bid * 256 + t) * 8;       // 8 elems/thread
        const float4 v0 = *(const float4*)&x[base];
        const float4 v1 = *(const float4*)&x[base + 4];
        short8 pk;
        pk[0] = f2bf_bits(v0.x); pk[1] = f2bf_bits(v0.y);
        pk[2] = f2bf_bits(v0.z); pk[3] = f2bf_bits(v0.w);
        pk[4] = f2bf_bits(v1.x); pk[5] = f2bf_bits(v1.y);
        pk[6] = f2bf_bits(v1.z); pk[7] = f2bf_bits(v1.w);
        *(short8*)&((short*)xb)[base] = pk;

        // ---- routing (single designated block) ----
        if (blockIdx.x == 0 && blockIdx.y == 0) {
            __shared__ int lcnt[E_];
            if (t < E_) lcnt[t] = 0;
            __syncthreads();
            const int lane = t & 63;
            const unsigned long long below = ((lane == 63) ? ~0ull : ((1ull << (lane + 1)) - 1)) >> 1;
#pragma unroll
            for (int i = 0; i < T_ / 256; i++) {
                const int tok = i * 256 + t;
                const float4 p = *(const float4*)&probs[(size_t)tok * E_];
                const float pv[4] = {p.x, p.y, p.z, p.w};
#pragma unroll
                for (int e = 0; e < E_; e++) {
                    const bool r = pv[e] > 0.0f;
                    const unsigned long long mask = __ballot(r);
                    int base_pos = 0;
                    if (lane == 0) base_pos = atomicAdd(&lcnt[e], __popcll(mask));
                    base_pos = __shfl(base_pos, 0);
                    const int pos = base_pos + (int)__popcll(mask & below);
                    if (r) { list[e * T_ + pos] = tok; slot[tok * E_ + e] = pos; }
                }
            }
            __syncthreads();
            if (t == 0) {
                int acc = 0;
#pragma unroll
                for (int e = 0; e < E_; e++) {
                    off_g[e] = acc; cnt_g[e] = lcnt[e];
                    acc += (lcnt[e] + 127) & ~127;
                }
                off_g[E_] = acc;
            }
        }
        return;
    }

    // ---- weight transpose paths (identical to R6, verified) ----
    __shared__ float tile[64 * 69 + 4];   // tile[c][r] at c*69 + r
    const float* src;
    __hip_bfloat16* dst;
    int r0, c0, C, dstStride;
    if (z < E_) {
        src = w1 + (size_t)z * H_ * F_;
        dst = w1t + (size_t)z * F_ * H_;
        C = F_; dstStride = H_;
        r0 = blockIdx.y * 64;   // over H
        c0 = blockIdx.x * 64;   // over F
    } else {
        const int e = z - E_;
        src = w2 + (size_t)e * F_ * H_;
        dst = w2t + (size_t)e * F_;     // element (r=f,c=h) -> dst[c*EF_ + r]
        C = H_; dstStride = EF_;
        r0 = blockIdx.x * 64;   // over F
        c0 = blockIdx.y * 64;   // over H
    }
    const int cl = (t & 15) * 4;
#pragma unroll
    for (int p = 0; p < 4; p++) {
        const int rl = (t >> 4) + 16 * p;
        const float4 v = *(const float4*)&src[(size_t)(r0 + rl) * C + (c0 + cl)];
        tile[(cl + 0) * 69 + rl] = v.x;
        tile[(cl + 1) * 69 + rl] = v.y;
        tile[(cl + 2) * 69 + rl] = v.z;
        tile[(cl + 3) * 69 + rl] = v.w;
    }
    __syncthreads();
    const int orow = (t & 7) * 8;
#pragma unroll
    for (int q = 0; q < 2; q++) {
        const int oc = (t >> 3) + 32 * q;
        short8 pk;
#pragma unroll
        for (int j = 0; j < 8; j++)
            pk[j] = f2bf_bits(tile[oc * 69 + orow + j]);
        *(short8*)&((short*)dst)[(size_t)(c0 + oc) * dstStride + r0 + orow] = pk;
    }
}

// LDS swizzle: row r chunk c stored at c ^ (r&7); staging fetches the permuted global
// chunk per lane; readers XOR. Conflict-free (verified R2: 2.5e7 -> 0).

// GEMM1 (gathered): Ag[off[e]+i][f] = bf16( p * gelu( (X[list[e][i]] @ W1_e)[f] ) )
__global__ __launch_bounds__(256)
void gemm1_kernel(const __hip_bfloat16* __restrict__ Xb,
                  const __hip_bfloat16* __restrict__ W1t,
                  const float* __restrict__ probs,
                  const int* __restrict__ cnt, const int* __restrict__ off,
                  const int* __restrict__ list,
                  __hip_bfloat16* __restrict__ Ag) {
    const int e  = blockIdx.z;
    const int ce = cnt[e];
    const int m0 = blockIdx.y * BM;
    if (m0 >= ce) return;
    const int n0 = blockIdx.x * BN;   // over F
    const __hip_bfloat16* Bt = W1t + (size_t)e * F_ * H_;
    __shared__ __align__(16) __hip_bfloat16 As[BM * BK];
    __shared__ __align__(16) __hip_bfloat16 Bs[BN * BK];
    const int tid = threadIdx.x, lane = tid & 63, wave = tid >> 6;
    const int wm = (wave >> 1) * 64, wn = (wave & 1) * 64;
    const int lr  = lane >> 3;
    const int lcg = ((lane & 7) ^ lr) * 8;

    int tokA[4];
#pragma unroll
    for (int j = 0; j < 4; j++) {
        int idx = m0 + (wave * 4 + j) * 8 + lr;
        if (idx >= ce) idx = ce - 1;          // clamp: dup row, store discarded below
        tokA[j] = list[e * T_ + idx];
    }

    f32x4 acc[4][4];
#pragma unroll
    for (int mi = 0; mi < 4; mi++)
#pragma unroll
        for (int ni = 0; ni < 4; ni++) acc[mi][ni] = (f32x4){0.f, 0.f, 0.f, 0.f};

    for (int k0 = 0; k0 < H_; k0 += BK) {
#pragma unroll
        for (int j = 0; j < 4; j++) {
            const int i = wave * 4 + j;
            const int r = i * 8 + lr;
            async_copy16(Xb + (size_t)tokA[j] * H_ + (k0 + lcg), (char*)As + i * 1024);
            async_copy16(Bt + (size_t)(n0 + r) * H_ + (k0 + lcg), (char*)Bs + i * 1024);
        }
        __syncthreads();
#pragma unroll
        for (int kt = 0; kt < BK / 32; kt++) {
            const int kq = kt * 4 + (lane >> 4);
            const int mr = lane & 15;
            const int sw = mr & 7;
            short8 aF[4], bF[4];
#pragma unroll
            for (int mi = 0; mi < 4; mi++)
                aF[mi] = *(const short8*)&As[(wm + mi * 16 + mr) * BK + ((kq ^ sw) << 3)];
#pragma unroll
            for (int ni = 0; ni < 4; ni++)
                bF[ni] = *(const short8*)&Bs[(wn + ni * 16 + mr) * BK + ((kq ^ sw) << 3)];
#pragma unroll
            for (int mi = 0; mi < 4; mi++)
#pragma unroll
                for (int ni = 0; ni < 4; ni++)
                    acc[mi][ni] = __builtin_amdgcn_mfma_f32_16x16x32_bf16(
                        aF[mi], bF[ni], acc[mi][ni], 0, 0, 0);
        }
        __syncthreads();
    }
    // C/D: col = lane&15, row = (lane>>4)*4 + reg
    const int rq = (lane >> 4) * 4, cq = lane & 15;
    const int obase = off[e] + m0;
#pragma unroll
    for (int mi = 0; mi < 4; mi++) {
#pragma unroll
        for (int reg = 0; reg < 4; reg++) {
            const int rl = wm + mi * 16 + rq + reg;
            int ci = m0 + rl; if (ci >= ce) ci = ce - 1;
            const int tok = list[e * T_ + ci];
            const float pv = probs[(size_t)tok * E_ + e];
#pragma unroll
            for (int ni = 0; ni < 4; ni++) {
                const int col = n0 + wn + ni * 16 + cq;
                const float v = acc[mi][ni][reg];
                // tanh-gelu via sigmoid: 0.5(1+tanh(u)) = sigma(2u); max dev vs erf-gelu ~3e-3
                const float u = 0.7978845608028654f * v * (1.0f + 0.044715f * v * v);
                const float g = v / (1.0f + __expf(-2.0f * u));
                Ag[(size_t)(obase + rl) * F_ + col] = __float2bfloat16(g * pv);
            }
        }
    }
}

// GEMM2 (gathered, split-K=KSPLIT, no atomics):
// Y[ks][off[e]+i][h] = (Ag_e @ W2_e)[i][h] over k in [ks*KS,(ks+1)*KS)
__global__ __launch_bounds__(256)
void gemm2_kernel(const __hip_bfloat16* __restrict__ Ag,
                  const __hip_bfloat16* __restrict__ W2t,
                  const int* __restrict__ cnt, const int* __restrict__ off,
                  __hip_bfloat16* __restrict__ Y) {
    const int e  = blockIdx.z >> 2, kh = blockIdx.z & 3;
    const int ce = cnt[e];
    const int m0 = blockIdx.y * BM;
    if (m0 >= ce) return;
    const int n0 = blockIdx.x * BN;   // over H
    const int oe = off[e];
    __shared__ __align__(16) __hip_bfloat16 As[BM * BK];
    __shared__ __align__(16) __hip_bfloat16 Bs[BN * BK];
    const int tid = threadIdx.x, lane = tid & 63, wave = tid >> 6;
    const int wm = (wave >> 1) * 64, wn = (wave & 1) * 64;
    const int lr  = lane >> 3;
    const int lcg = ((lane & 7) ^ lr) * 8;
    const __hip_bfloat16* Abase = Ag + (size_t)oe * F_ + kh * KS;
    const __hip_bfloat16* Bbase = W2t + (size_t)e * F_ + kh * KS;

    f32x4 acc[4][4];
#pragma unroll
    for (int mi = 0; mi < 4; mi++)
#pragma unroll
        for (int ni = 0; ni < 4; ni++) acc[mi][ni] = (f32x4){0.f, 0.f, 0.f, 0.f};

    for (int k0 = 0; k0 < KS; k0 += BK) {
#pragma unroll
        for (int j = 0; j < 4; j++) {
            const int i = wave * 4 + j;
            const int r = i * 8 + lr;
            async_copy16(Abase + (size_t)(m0 + r) * F_ + (k0 + lcg), (char*)As + i * 1024);
            async_copy16(Bbase + (size_t)(n0 + r) * EF_ + (k0 + lcg), (char*)Bs + i * 1024);
        }
        __syncthreads();
#pragma unroll
        for (int kt = 0; kt < BK / 32; kt++) {
            const int kq = kt * 4 + (lane >> 4);
            const int mr = lane & 15;
            const int sw = mr & 7;
            short8 aF[4], bF[4];
#pragma unroll
            for (int mi = 0; mi < 4; mi++)
                aF[mi] = *(const short8*)&As[(wm + mi * 16 + mr) * BK + ((kq ^ sw) << 3)];
#pragma unroll
            for (int ni = 0; ni < 4; ni++)
                bF[ni] = *(const short8*)&Bs[(wn + ni * 16 + mr) * BK + ((kq ^ sw) << 3)];
#pragma unroll
            for (int mi = 0; mi < 4; mi++)
#pragma unroll
                for (int ni = 0; ni < 4; ni++)
                    acc[mi][ni] = __builtin_amdgcn_mfma_f32_16x16x32_bf16(
                        aF[mi], bF[ni], acc[mi][ni], 0, 0, 0);
        }
        __syncthreads();
    }
    const int rq = (lane >> 4) * 4, cq = lane & 15;
    __hip_bfloat16* Yk = Y + (size_t)kh * ROWCAP * H_ + (size_t)(oe + m0) * H_;
#pragma unroll
    for (int mi = 0; mi < 4; mi++)
#pragma unroll
        for (int reg = 0; reg < 4; reg++) {
            const int rl = wm + mi * 16 + rq + reg;
#pragma unroll
            for (int ni = 0; ni < 4; ni++) {
                const int col = n0 + wn + ni * 16 + cq;
                Yk[(size_t)rl * H_ + col] = __float2bfloat16(acc[mi][ni][reg]);
            }
        }
}

// out[t][h] = res[t][h] + sum_{e routed} sum_{ks} Y[ks][off[e]+slot[t][e]][h]
__global__ __launch_bounds__(256)
void combine_kernel(const float* __restrict__ res, const float* __restrict__ probs,
                    const int* __restrict__ off, const int* __restrict__ slot,
                    const __hip_bfloat16* __restrict__ Y, float* __restrict__ out) {
    const int idx = blockIdx.x * 256 + threadIdx.x;   // T_*(H_/4) threads
    const int t  = idx >> 8;
    const int hc = (idx & 255) * 4;
    const float4 r = ((const float4*)res)[idx];
    float s0 = r.x, s1 = r.y, s2 = r.z, s3 = r.w;
#pragma unroll
    for (int e = 0; e < E_; e++) {
        if (probs[(size_t)t * E_ + e] > 0.0f) {
            const int row = off[e] + slot[(size_t)t * E_ + e];
#pragma unroll
            for (int ks = 0; ks < KSPLIT; ks++) {
                const ushort4 y = *(const ushort4*)&Y[((size_t)ks * ROWCAP + row) * H_ + hc];
                s0 += bf2f(y.x); s1 += bf2f(y.y); s2 += bf2f(y.z); s3 += bf2f(y.w);
            }
        }
    }
    ((float4*)out)[idx] = make_float4(s0, s1, s2, s3);
}

extern "C" void kernel_launch(void* const* d_in, const int* in_sizes, int n_in,
                              void* d_out, int out_size, void* d_ws, size_t ws_size,
                              hipStream_t stream) {
    const float* x     = (const float*)d_in[0];
    const float* res   = (const float*)d_in[1];
    const float* probs = (const float*)d_in[2];
    const float* w1    = (const float*)d_in[4];
    const float* w2    = (const float*)d_in[5];
    float* out = (float*)d_out;

    char* ws = (char*)d_ws;
    // Y (36 MiB) ALIASES Xb+W1t: both are dead after gemm1, and gemm2 (writes Y)
    // runs after gemm1 in stream order. Every call rewrites Xb/W1t before gemm1.
    __hip_bfloat16* Y   = (__hip_bfloat16*)(ws);                 // 36 MiB (KSPLIT slices)
    __hip_bfloat16* Xb  = (__hip_bfloat16*)(ws);                 //  4 MiB (dead after gemm1)
    __hip_bfloat16* W1t = (__hip_bfloat16*)(ws + (4ull  << 20)); // 32 MiB (dead after gemm1)
    __hip_bfloat16* W2t = (__hip_bfloat16*)(ws + (36ull << 20)); // 32 MiB
    __hip_bfloat16* Ag  = (__hip_bfloat16*)(ws + (68ull << 20)); // 36 MiB
    char* meta = ws + (104ull << 20);
    int* cnt  = (int*)meta;                       // 4 ints
    int* off  = (int*)(meta + 64);                // 5 ints
    int* list = (int*)(meta + 256);               // E*T ints = 32 KB
    int* slot = (int*)(meta + 256 + 4 * T_ * 4);  // T*E ints = 32 KB

    // 4 graph nodes total (was 9): prep, gemm1, gemm2, combine.
    trans_kernel<<<dim3(64, 16, 2 * E_ + 1), dim3(256), 0, stream>>>(
        w1, w2, x, probs, W1t, W2t, Xb, cnt, off, list, slot);
    gemm1_kernel<<<dim3(F_ / BN, T_ / BM, E_), dim3(256), 0, stream>>>(
        Xb, W1t, probs, cnt, off, list, Ag);
    gemm2_kernel<<<dim3(H_ / BN, T_ / BM, KSPLIT * E_), dim3(256), 0, stream>>>(
        Ag, W2t, cnt, off, Y);
    combine_kernel<<<dim3(T_ * (H_ / 4) / 256), dim3(256), 0, stream>>>(
        res, probs, off, slot, Y, out);
}